// Round 4
// baseline (255.008 us; speedup 1.0000x reference)
//
#include <hip/hip_runtime.h>
#include <hip/hip_cooperative_groups.h>

namespace cg = cooperative_groups;

#define G 16
#define T 4096
#define DD 64

typedef __attribute__((ext_vector_type(8))) short bf16x8;
typedef __attribute__((ext_vector_type(4))) float f32x4;
typedef unsigned short U16;

__device__ __forceinline__ float bf2f(U16 u) {
  union { unsigned int u; float f; } x; x.u = ((unsigned int)u) << 16; return x.f;
}
__device__ __forceinline__ U16 f2bf(float f) {
  union { float f; unsigned int u; } x; x.f = f;
  unsigned int r = x.u + 0x7FFFu + ((x.u >> 16) & 1u);
  return (U16)(r >> 16);
}

#define MFMA(a, b, c) __builtin_amdgcn_mfma_f32_16x16x32_bf16((a), (b), (c), 0, 0, 0)

// ln(10000)/32
#define ROPE_C 0.28782313662425575f

// ============================================================================
// Path 1: fused cooperative kernel (single dispatch)
// ============================================================================
__global__ __launch_bounds__(256, 4) void k_fused(const float* __restrict__ Q,
                                                  const float* __restrict__ K,
                                                  const float* __restrict__ V,
                                                  float* __restrict__ Out,
                                                  U16* __restrict__ Kr,
                                                  U16* __restrict__ Xu) {
  __shared__ __align__(16) U16 KrT[64][72];    // phase A: [d][k]; phase C: reused as SP [e][d]
  __shared__ __align__(16) U16 VT[64][72];     // [e][k] — persists A -> C
  __shared__ __align__(16) U16 SW[4][16][72];  // phase C per-wave masked S round-trip

  int wid = blockIdx.x;            // g*64 + b
  int g = wid >> 6, b = wid & 63;
  int k0 = b * 64;
  int tid = threadIdx.x;
  int lane = tid & 63, wv = tid >> 6;
  int lr = lane & 15, lg = lane >> 4;

  // ---- Phase A: rope K -> KrT (LDS) + Kr (global); V -> VT; X_b = V^T Kr ----
  {
    int r = tid >> 2, qq = tid & 3, d0 = qq * 8;
    int t = k0 + r;
    size_t base = ((size_t)g * T + t) * DD;
    const float* rp = K + base;
    float x1[8], x2[8];
    *(float4*)&x1[0] = *(const float4*)(rp + d0);
    *(float4*)&x1[4] = *(const float4*)(rp + d0 + 4);
    *(float4*)&x2[0] = *(const float4*)(rp + d0 + 32);
    *(float4*)&x2[4] = *(const float4*)(rp + d0 + 36);
    bf16x8 v1, v2;
#pragma unroll
    for (int i = 0; i < 8; ++i) {
      float invf = __expf(-(float)(d0 + i) * ROPE_C);
      float ang = (float)t * invf;
      float s, c;
      __sincosf(ang, &s, &c);
      float o1 = x1[i] * c - x2[i] * s;
      float o2 = x1[i] * s + x2[i] * c;
      U16 b1 = f2bf(o1), b2 = f2bf(o2);
      v1[i] = (short)b1; v2[i] = (short)b2;
      KrT[d0 + i][r]      = b1;
      KrT[d0 + i + 32][r] = b2;
    }
    *(bf16x8*)(Kr + base + d0)      = v1;
    *(bf16x8*)(Kr + base + d0 + 32) = v2;
  }
  {
    int c = tid & 63, r0 = (tid >> 6) * 16;
#pragma unroll
    for (int h = 0; h < 2; ++h) {
      bf16x8 tv;
#pragma unroll
      for (int i = 0; i < 8; ++i)
        tv[i] = (short)f2bf(V[((size_t)g * T + k0 + r0 + h * 8 + i) * DD + c]);
      *(bf16x8*)&VT[c][r0 + h * 8] = tv;
    }
  }
  __syncthreads();
  {
    bf16x8 A0 = *(const bf16x8*)&VT[16 * wv + lr][8 * lg];
    bf16x8 A1 = *(const bf16x8*)&VT[16 * wv + lr][8 * lg + 32];
#pragma unroll
    for (int dt = 0; dt < 4; ++dt) {
      bf16x8 B0 = *(const bf16x8*)&KrT[16 * dt + lr][8 * lg];
      bf16x8 B1 = *(const bf16x8*)&KrT[16 * dt + lr][8 * lg + 32];
      f32x4 acc = {0.f, 0.f, 0.f, 0.f};
      acc = MFMA(A0, B0, acc);
      acc = MFMA(A1, B1, acc);
#pragma unroll
      for (int rr = 0; rr < 4; ++rr) {
        int e = 16 * wv + 4 * lg + rr, d = 16 * dt + lr;
        Xu[((size_t)wid << 12) + e * 64 + d] = f2bf(acc[rr]);
      }
    }
  }

  cg::this_grid().sync();

  // ---- Phase B: exclusive prefix over 64 block matrices per head (4 threads/chain) ----
  {
    int tau = wid * 256 + tid;          // 262144 threads
    int chain = tau >> 2, seg = tau & 3;
    int cg_ = chain >> 12, col = chain & 4095;
    size_t base = ((size_t)cg_ << 18) + ((size_t)(seg * 16) << 12) + col;
    U16 v[16];
#pragma unroll
    for (int i = 0; i < 16; ++i)
      v[i] = Xu[base + ((size_t)i << 12)];
    float s = 0.f;
#pragma unroll
    for (int i = 0; i < 16; ++i) s += bf2f(v[i]);
    float b1 = __shfl_up(s, 1, 4);
    float b2 = __shfl_up(s, 2, 4);
    float b3 = __shfl_up(s, 3, 4);
    float run = 0.f;
    if (seg > 0) run += b1;
    if (seg > 1) run += b2;
    if (seg > 2) run += b3;
#pragma unroll
    for (int i = 0; i < 16; ++i) {
      float f = bf2f(v[i]);
      Xu[base + ((size_t)i << 12)] = f2bf(run);
      run += f;
    }
  }

  cg::this_grid().sync();

  // ---- Phase C: O_b = rope(Q)_b * Sp_b + tril_strict(rope(Q)_b Kr_b^T) V_b ----
  U16 (*SP)[72] = KrT;   // reuse KrT space for Sp^T [e][d]
  {
    int r = tid >> 2, c0 = (tid & 3) * 16;
    const U16* src = Xu + ((size_t)wid << 12) + r * 64 + c0;
    bf16x8 a = *(const bf16x8*)src;
    bf16x8 bb = *(const bf16x8*)(src + 8);
    __syncthreads();
    *(bf16x8*)&SP[r][c0]     = a;
    *(bf16x8*)&SP[r][c0 + 8] = bb;
  }

  int q0 = k0 + 16 * wv;

  bf16x8 Aq0, Aq1;
  {
    int t = q0 + lr;
    const float* qrow = Q + ((size_t)g * T + t) * DD;
    float x1[8], x2[8];
    *(float4*)&x1[0] = *(const float4*)(qrow + 8 * lg);
    *(float4*)&x1[4] = *(const float4*)(qrow + 8 * lg + 4);
    *(float4*)&x2[0] = *(const float4*)(qrow + 8 * lg + 32);
    *(float4*)&x2[4] = *(const float4*)(qrow + 8 * lg + 36);
#pragma unroll
    for (int i = 0; i < 8; ++i) {
      float invf = __expf(-(float)(8 * lg + i) * ROPE_C);
      float ang = (float)t * invf;
      float s, c;
      __sincosf(ang, &s, &c);
      Aq0[i] = (short)f2bf(x1[i] * c - x2[i] * s);
      Aq1[i] = (short)f2bf(x1[i] * s + x2[i] * c);
    }
  }
  __syncthreads();

  f32x4 O[4];
#pragma unroll
  for (int et = 0; et < 4; ++et) O[et] = (f32x4){0.f, 0.f, 0.f, 0.f};

#pragma unroll
  for (int et = 0; et < 4; ++et) {
    bf16x8 B0 = *(const bf16x8*)&SP[16 * et + lr][8 * lg];
    bf16x8 B1 = *(const bf16x8*)&SP[16 * et + lr][8 * lg + 32];
    O[et] = MFMA(Aq0, B0, O[et]);
    O[et] = MFMA(Aq1, B1, O[et]);
  }

  for (int kt = 0; kt <= wv; ++kt) {
    const U16* krow = Kr + ((size_t)g * T + k0 + 16 * kt + lr) * DD;
    bf16x8 Bk0 = *(const bf16x8*)(krow + 8 * lg);
    bf16x8 Bk1 = *(const bf16x8*)(krow + 8 * lg + 32);
    f32x4 s = {0.f, 0.f, 0.f, 0.f};
    s = MFMA(Aq0, Bk0, s);
    s = MFMA(Aq1, Bk1, s);
#pragma unroll
    for (int rr = 0; rr < 4; ++rr) {
      int qi = 16 * wv + 4 * lg + rr, ki = 16 * kt + lr;
      float val = (qi > ki) ? s[rr] : 0.f;
      SW[wv][4 * lg + rr][16 * kt + lr] = f2bf(val);
    }
  }
  for (int kt = wv + 1; kt < 4; ++kt) {
#pragma unroll
    for (int rr = 0; rr < 4; ++rr)
      SW[wv][4 * lg + rr][16 * kt + lr] = 0;
  }

  bf16x8 As0 = *(const bf16x8*)&SW[wv][lr][8 * lg];
  bf16x8 As1 = *(const bf16x8*)&SW[wv][lr][8 * lg + 32];

#pragma unroll
  for (int et = 0; et < 4; ++et) {
    bf16x8 Bv0 = *(const bf16x8*)&VT[16 * et + lr][8 * lg];
    bf16x8 Bv1 = *(const bf16x8*)&VT[16 * et + lr][8 * lg + 32];
    O[et] = MFMA(As0, Bv0, O[et]);
    O[et] = MFMA(As1, Bv1, O[et]);
  }

#pragma unroll
  for (int et = 0; et < 4; ++et)
#pragma unroll
    for (int rr = 0; rr < 4; ++rr)
      Out[((size_t)g * T + q0 + 4 * lg + rr) * DD + 16 * et + lr] = O[et][rr];
}

// ============================================================================
// Path 2: fallback — proven R2 pipeline + parallelized phase 2
// ============================================================================
__global__ __launch_bounds__(256) void k_tab(float2* __restrict__ tab) {
  int idx = blockIdx.x * 256 + threadIdx.x;   // 131072
  int t = idx >> 5, j = idx & 31;
  float invf = expf(-(float)j * ROPE_C);
  float ang = (float)t * invf;
  tab[idx] = make_float2(cosf(ang), sinf(ang));
}

__global__ __launch_bounds__(256) void k_phase1(const float* __restrict__ K, const float* __restrict__ V,
                                                const float2* __restrict__ tab,
                                                U16* __restrict__ Kr, U16* __restrict__ Xu) {
  __shared__ __align__(16) U16 KrT[64][72];
  __shared__ __align__(16) U16 VT[64][72];
  int wid = blockIdx.x;
  int g = wid >> 6, b = wid & 63;
  int k0 = b * 64;
  int tid = threadIdx.x;
  {
    int r = tid >> 2, qq = tid & 3, d0 = qq * 8;
    int t = k0 + r;
    size_t base = ((size_t)g * T + t) * DD;
    const float* rp = K + base;
    const float2* tp = tab + t * 32 + d0;
    float x1[8], x2[8];
    *(float4*)&x1[0] = *(const float4*)(rp + d0);
    *(float4*)&x1[4] = *(const float4*)(rp + d0 + 4);
    *(float4*)&x2[0] = *(const float4*)(rp + d0 + 32);
    *(float4*)&x2[4] = *(const float4*)(rp + d0 + 36);
    bf16x8 v1, v2;
#pragma unroll
    for (int i = 0; i < 8; ++i) {
      float2 cs = tp[i];
      float o1 = x1[i] * cs.x - x2[i] * cs.y;
      float o2 = x1[i] * cs.y + x2[i] * cs.x;
      U16 b1 = f2bf(o1), b2 = f2bf(o2);
      v1[i] = (short)b1; v2[i] = (short)b2;
      KrT[d0 + i][r]      = b1;
      KrT[d0 + i + 32][r] = b2;
    }
    *(bf16x8*)(Kr + base + d0)      = v1;
    *(bf16x8*)(Kr + base + d0 + 32) = v2;
  }
  {
    int c = tid & 63, r0 = (tid >> 6) * 16;
#pragma unroll
    for (int h = 0; h < 2; ++h) {
      bf16x8 tv;
#pragma unroll
      for (int i = 0; i < 8; ++i)
        tv[i] = (short)f2bf(V[((size_t)g * T + k0 + r0 + h * 8 + i) * DD + c]);
      *(bf16x8*)&VT[c][r0 + h * 8] = tv;
    }
  }
  __syncthreads();
  int lane = tid & 63, wv = tid >> 6;
  int lr = lane & 15, lg = lane >> 4;
  bf16x8 A0 = *(const bf16x8*)&VT[16 * wv + lr][8 * lg];
  bf16x8 A1 = *(const bf16x8*)&VT[16 * wv + lr][8 * lg + 32];
#pragma unroll
  for (int dt = 0; dt < 4; ++dt) {
    bf16x8 B0 = *(const bf16x8*)&KrT[16 * dt + lr][8 * lg];
    bf16x8 B1 = *(const bf16x8*)&KrT[16 * dt + lr][8 * lg + 32];
    f32x4 acc = {0.f, 0.f, 0.f, 0.f};
    acc = MFMA(A0, B0, acc);
    acc = MFMA(A1, B1, acc);
#pragma unroll
    for (int rr = 0; rr < 4; ++rr) {
      int e = 16 * wv + 4 * lg + rr, d = 16 * dt + lr;
      Xu[((size_t)wid << 12) + e * 64 + d] = f2bf(acc[rr]);
    }
  }
}

__global__ __launch_bounds__(256) void k_phase2b(U16* __restrict__ Xu) {
  int tau = blockIdx.x * 256 + threadIdx.x;   // 262144
  int chain = tau >> 2, seg = tau & 3;
  int cg_ = chain >> 12, col = chain & 4095;
  size_t base = ((size_t)cg_ << 18) + ((size_t)(seg * 16) << 12) + col;
  U16 v[16];
#pragma unroll
  for (int i = 0; i < 16; ++i)
    v[i] = Xu[base + ((size_t)i << 12)];
  float s = 0.f;
#pragma unroll
  for (int i = 0; i < 16; ++i) s += bf2f(v[i]);
  float b1 = __shfl_up(s, 1, 4);
  float b2 = __shfl_up(s, 2, 4);
  float b3 = __shfl_up(s, 3, 4);
  float run = 0.f;
  if (seg > 0) run += b1;
  if (seg > 1) run += b2;
  if (seg > 2) run += b3;
#pragma unroll
  for (int i = 0; i < 16; ++i) {
    float f = bf2f(v[i]);
    Xu[base + ((size_t)i << 12)] = f2bf(run);
    run += f;
  }
}

__global__ __launch_bounds__(256) void k_phase3(const float* __restrict__ Q, const U16* __restrict__ Kr,
                                                const float* __restrict__ V, const U16* __restrict__ Xu,
                                                const float2* __restrict__ tab,
                                                float* __restrict__ Out) {
  __shared__ __align__(16) U16 SP[64][72];
  __shared__ __align__(16) U16 VT[64][72];
  __shared__ __align__(16) U16 SW[4][16][72];
  int wid = blockIdx.x;
  int g = wid >> 6, b = wid & 63;
  int k0 = b * 64;
  int tid = threadIdx.x;
  {
    int r = tid >> 2, c0 = (tid & 3) * 16;
    const U16* src = Xu + ((size_t)wid << 12) + r * 64 + c0;
    *(bf16x8*)&SP[r][c0]     = *(const bf16x8*)src;
    *(bf16x8*)&SP[r][c0 + 8] = *(const bf16x8*)(src + 8);
  }
  {
    int c = tid & 63, r0 = (tid >> 6) * 16;
#pragma unroll
    for (int h = 0; h < 2; ++h) {
      bf16x8 tv;
#pragma unroll
      for (int i = 0; i < 8; ++i)
        tv[i] = (short)f2bf(V[((size_t)g * T + k0 + r0 + h * 8 + i) * DD + c]);
      *(bf16x8*)&VT[c][r0 + h * 8] = tv;
    }
  }
  int lane = tid & 63, wv = tid >> 6;
  int lr = lane & 15, lg = lane >> 4;
  int q0 = k0 + 16 * wv;
  bf16x8 Aq0, Aq1;
  {
    int t = q0 + lr;
    const float* qrow = Q + ((size_t)g * T + t) * DD;
    const float2* tp = tab + t * 32 + 8 * lg;
    float x1[8], x2[8];
    *(float4*)&x1[0] = *(const float4*)(qrow + 8 * lg);
    *(float4*)&x1[4] = *(const float4*)(qrow + 8 * lg + 4);
    *(float4*)&x2[0] = *(const float4*)(qrow + 8 * lg + 32);
    *(float4*)&x2[4] = *(const float4*)(qrow + 8 * lg + 36);
#pragma unroll
    for (int i = 0; i < 8; ++i) {
      float2 cs = tp[i];
      Aq0[i] = (short)f2bf(x1[i] * cs.x - x2[i] * cs.y);
      Aq1[i] = (short)f2bf(x1[i] * cs.y + x2[i] * cs.x);
    }
  }
  __syncthreads();

  f32x4 O[4];
#pragma unroll
  for (int et = 0; et < 4; ++et) O[et] = (f32x4){0.f, 0.f, 0.f, 0.f};

#pragma unroll
  for (int et = 0; et < 4; ++et) {
    bf16x8 B0 = *(const bf16x8*)&SP[16 * et + lr][8 * lg];
    bf16x8 B1 = *(const bf16x8*)&SP[16 * et + lr][8 * lg + 32];
    O[et] = MFMA(Aq0, B0, O[et]);
    O[et] = MFMA(Aq1, B1, O[et]);
  }

  for (int kt = 0; kt <= wv; ++kt) {
    const U16* krow = Kr + ((size_t)g * T + k0 + 16 * kt + lr) * DD;
    bf16x8 Bk0 = *(const bf16x8*)(krow + 8 * lg);
    bf16x8 Bk1 = *(const bf16x8*)(krow + 8 * lg + 32);
    f32x4 s = {0.f, 0.f, 0.f, 0.f};
    s = MFMA(Aq0, Bk0, s);
    s = MFMA(Aq1, Bk1, s);
#pragma unroll
    for (int rr = 0; rr < 4; ++rr) {
      int qi = 16 * wv + 4 * lg + rr, ki = 16 * kt + lr;
      float val = (qi > ki) ? s[rr] : 0.f;
      SW[wv][4 * lg + rr][16 * kt + lr] = f2bf(val);
    }
  }
  for (int kt = wv + 1; kt < 4; ++kt) {
#pragma unroll
    for (int rr = 0; rr < 4; ++rr)
      SW[wv][4 * lg + rr][16 * kt + lr] = 0;
  }

  bf16x8 As0 = *(const bf16x8*)&SW[wv][lr][8 * lg];
  bf16x8 As1 = *(const bf16x8*)&SW[wv][lr][8 * lg + 32];

#pragma unroll
  for (int et = 0; et < 4; ++et) {
    bf16x8 Bv0 = *(const bf16x8*)&VT[16 * et + lr][8 * lg];
    bf16x8 Bv1 = *(const bf16x8*)&VT[16 * et + lr][8 * lg + 32];
    O[et] = MFMA(As0, Bv0, O[et]);
    O[et] = MFMA(As1, Bv1, O[et]);
  }

#pragma unroll
  for (int et = 0; et < 4; ++et)
#pragma unroll
    for (int rr = 0; rr < 4; ++rr)
      Out[((size_t)g * T + q0 + 4 * lg + rr) * DD + 16 * et + lr] = O[et][rr];
}

extern "C" void kernel_launch(void* const* d_in, const int* in_sizes, int n_in,
                              void* d_out, int out_size, void* d_ws, size_t ws_size,
                              hipStream_t stream) {
  const float* Q = (const float*)d_in[0];
  const float* K = (const float*)d_in[1];
  const float* V = (const float*)d_in[2];
  float* Out = (float*)d_out;
  U16* W  = (U16*)d_ws;
  U16* Kr = W;                            // 8.39 MB
  U16* Xu = W + 4194304;                  // 8.39 MB
  float2* tab = (float2*)(W + 8388608);   // 1.05 MB

  void* args[] = { (void*)&Q, (void*)&K, (void*)&V, (void*)&Out, (void*)&Kr, (void*)&Xu };
  hipError_t err = hipLaunchCooperativeKernel((void*)k_fused, dim3(G * 64), dim3(256),
                                              args, 0, stream);
  if (err != hipSuccess) {
    // deterministic fallback: same math, 4 dispatches
    k_tab<<<512, 256, 0, stream>>>(tab);
    k_phase1<<<G * 64, 256, 0, stream>>>(K, V, tab, Kr, Xu);
    k_phase2b<<<1024, 256, 0, stream>>>(Xu);
    k_phase3<<<G * 64, 256, 0, stream>>>(Q, Kr, V, Xu, tab, Out);
  }
}

// Round 5
// 32.141 us; speedup vs baseline: 7.9341x; 7.9341x over previous
//
#include <hip/hip_runtime.h>

#define G 16
#define T 4096
#define DD 64

typedef __attribute__((ext_vector_type(8))) short bf16x8;
typedef __attribute__((ext_vector_type(4))) float f32x4;
typedef unsigned short U16;

__device__ __forceinline__ float bf2f(U16 u) {
  union { unsigned int u; float f; } x; x.u = ((unsigned int)u) << 16; return x.f;
}
__device__ __forceinline__ U16 f2bf(float f) {
  union { float f; unsigned int u; } x; x.f = f;
  unsigned int r = x.u + 0x7FFFu + ((x.u >> 16) & 1u);
  return (U16)(r >> 16);
}

#define MFMA(a, b, c) __builtin_amdgcn_mfma_f32_16x16x32_bf16((a), (b), (c), 0, 0, 0)

// ln(10000)/32
#define ROPE_C 0.28782313662425575f

// ---------------- Phase 1: rope K -> Kr + KrT; V -> Vb (bf16) + VT; X_b = V^T Kr ----------------
__global__ __launch_bounds__(256) void k_phase1(const float* __restrict__ K, const float* __restrict__ V,
                                                U16* __restrict__ Kr, U16* __restrict__ Vb,
                                                U16* __restrict__ Xu) {
  __shared__ __align__(16) U16 KrT[64][72];   // [d][k]
  __shared__ __align__(16) U16 VT[64][72];    // [e][k]
  int wid = blockIdx.x;            // g*64 + b
  int g = wid >> 6, b = wid & 63;
  int k0 = b * 64;
  int tid = threadIdx.x;

  int r = tid >> 2, qq = tid & 3, d0 = qq * 8;
  int t = k0 + r;
  size_t base = ((size_t)g * T + t) * DD;

  // K path: rope (inline trig) -> Kr global + KrT LDS
  {
    const float* rp = K + base;
    float x1[8], x2[8];
    *(float4*)&x1[0] = *(const float4*)(rp + d0);
    *(float4*)&x1[4] = *(const float4*)(rp + d0 + 4);
    *(float4*)&x2[0] = *(const float4*)(rp + d0 + 32);
    *(float4*)&x2[4] = *(const float4*)(rp + d0 + 36);
    bf16x8 v1, v2;
#pragma unroll
    for (int i = 0; i < 8; ++i) {
      float invf = __expf(-(float)(d0 + i) * ROPE_C);
      float ang = (float)t * invf;
      float s, c;
      __sincosf(ang, &s, &c);
      float o1 = x1[i] * c - x2[i] * s;
      float o2 = x1[i] * s + x2[i] * c;
      U16 b1 = f2bf(o1), b2 = f2bf(o2);
      v1[i] = (short)b1; v2[i] = (short)b2;
      KrT[d0 + i][r]      = b1;
      KrT[d0 + i + 32][r] = b2;
    }
    *(bf16x8*)(Kr + base + d0)      = v1;
    *(bf16x8*)(Kr + base + d0 + 32) = v2;
  }
  // V path: f32 -> bf16, Vb global + VT LDS (transposed)
  {
    const float* vp = V + base;
    float y1[8], y2[8];
    *(float4*)&y1[0] = *(const float4*)(vp + d0);
    *(float4*)&y1[4] = *(const float4*)(vp + d0 + 4);
    *(float4*)&y2[0] = *(const float4*)(vp + d0 + 32);
    *(float4*)&y2[4] = *(const float4*)(vp + d0 + 36);
    bf16x8 w1, w2;
#pragma unroll
    for (int i = 0; i < 8; ++i) {
      U16 b1 = f2bf(y1[i]), b2 = f2bf(y2[i]);
      w1[i] = (short)b1; w2[i] = (short)b2;
      VT[d0 + i][r]      = b1;
      VT[d0 + i + 32][r] = b2;
    }
    *(bf16x8*)(Vb + base + d0)      = w1;
    *(bf16x8*)(Vb + base + d0 + 32) = w2;
  }
  __syncthreads();

  int lane = tid & 63, wv = tid >> 6;
  int lr = lane & 15, lg = lane >> 4;
  bf16x8 A0 = *(const bf16x8*)&VT[16 * wv + lr][8 * lg];
  bf16x8 A1 = *(const bf16x8*)&VT[16 * wv + lr][8 * lg + 32];
#pragma unroll
  for (int dt = 0; dt < 4; ++dt) {
    bf16x8 B0 = *(const bf16x8*)&KrT[16 * dt + lr][8 * lg];
    bf16x8 B1 = *(const bf16x8*)&KrT[16 * dt + lr][8 * lg + 32];
    f32x4 acc = {0.f, 0.f, 0.f, 0.f};
    acc = MFMA(A0, B0, acc);
    acc = MFMA(A1, B1, acc);
#pragma unroll
    for (int rr = 0; rr < 4; ++rr) {
      int e = 16 * wv + 4 * lg + rr, d = 16 * dt + lr;
      Xu[((size_t)wid << 12) + e * 64 + d] = f2bf(acc[rr]);
    }
  }
}

// ---------------- Phase 2: exclusive prefix over 64 block matrices per head (4 threads/chain) ----------------
__global__ __launch_bounds__(256) void k_phase2b(U16* __restrict__ Xu) {
  int tau = blockIdx.x * 256 + threadIdx.x;   // 262144
  int chain = tau >> 2, seg = tau & 3;
  int hd = chain >> 12, col = chain & 4095;
  size_t base = ((size_t)hd << 18) + ((size_t)(seg * 16) << 12) + col;
  U16 v[16];
#pragma unroll
  for (int i = 0; i < 16; ++i)
    v[i] = Xu[base + ((size_t)i << 12)];
  float s = 0.f;
#pragma unroll
  for (int i = 0; i < 16; ++i) s += bf2f(v[i]);
  float b1 = __shfl_up(s, 1, 4);
  float b2 = __shfl_up(s, 2, 4);
  float b3 = __shfl_up(s, 3, 4);
  float run = 0.f;
  if (seg > 0) run += b1;
  if (seg > 1) run += b2;
  if (seg > 2) run += b3;
#pragma unroll
  for (int i = 0; i < 16; ++i) {
    float f = bf2f(v[i]);
    Xu[base + ((size_t)i << 12)] = f2bf(run);
    run += f;
  }
}

// ---------------- Phase 3: O_b = rope(Q)_b * Sp_b + tril_strict(rope(Q)_b Kr_b^T) V_b ----------------
__global__ __launch_bounds__(256) void k_phase3(const float* __restrict__ Q, const U16* __restrict__ Kr,
                                                const U16* __restrict__ Vb, const U16* __restrict__ Xu,
                                                float* __restrict__ Out) {
  __shared__ __align__(16) U16 SP[64][72];     // Sp^T [e][d]
  __shared__ __align__(16) U16 VT[64][72];     // [e][k]
  __shared__ __align__(16) U16 SW[4][16][72];  // per-wave masked S round-trip
  int wid = blockIdx.x;
  int g = wid >> 6, b = wid & 63;
  int k0 = b * 64;
  int tid = threadIdx.x;

  // stage Sp^T (vector copy from Xu)
  {
    int r = tid >> 2, c0 = (tid & 3) * 16;
    const U16* src = Xu + ((size_t)wid << 12) + r * 64 + c0;
    *(bf16x8*)&SP[r][c0]     = *(const bf16x8*)src;
    *(bf16x8*)&SP[r][c0 + 8] = *(const bf16x8*)(src + 8);
  }
  // stage VT from bf16 Vb (vector load + scalar scatter)
  {
    int r = tid >> 2, qq = tid & 3, d0 = qq * 8;
    size_t base = ((size_t)g * T + k0 + r) * DD;
    bf16x8 a0 = *(const bf16x8*)(Vb + base + d0);
    bf16x8 a1 = *(const bf16x8*)(Vb + base + d0 + 32);
#pragma unroll
    for (int i = 0; i < 8; ++i) {
      VT[d0 + i][r]      = (U16)a0[i];
      VT[d0 + i + 32][r] = (U16)a1[i];
    }
  }

  int lane = tid & 63, wv = tid >> 6;
  int lr = lane & 15, lg = lane >> 4;
  int q0 = k0 + 16 * wv;

  // fused RoPE(Q) in-register (inline trig)
  bf16x8 Aq0, Aq1;
  {
    int t = q0 + lr;
    const float* qrow = Q + ((size_t)g * T + t) * DD;
    float x1[8], x2[8];
    *(float4*)&x1[0] = *(const float4*)(qrow + 8 * lg);
    *(float4*)&x1[4] = *(const float4*)(qrow + 8 * lg + 4);
    *(float4*)&x2[0] = *(const float4*)(qrow + 8 * lg + 32);
    *(float4*)&x2[4] = *(const float4*)(qrow + 8 * lg + 36);
#pragma unroll
    for (int i = 0; i < 8; ++i) {
      float invf = __expf(-(float)(8 * lg + i) * ROPE_C);
      float ang = (float)t * invf;
      float s, c;
      __sincosf(ang, &s, &c);
      Aq0[i] = (short)f2bf(x1[i] * c - x2[i] * s);
      Aq1[i] = (short)f2bf(x1[i] * s + x2[i] * c);
    }
  }
  __syncthreads();

  f32x4 O[4];
#pragma unroll
  for (int et = 0; et < 4; ++et) O[et] = (f32x4){0.f, 0.f, 0.f, 0.f};

  // term 1: Qr * Sp
#pragma unroll
  for (int et = 0; et < 4; ++et) {
    bf16x8 B0 = *(const bf16x8*)&SP[16 * et + lr][8 * lg];
    bf16x8 B1 = *(const bf16x8*)&SP[16 * et + lr][8 * lg + 32];
    O[et] = MFMA(Aq0, B0, O[et]);
    O[et] = MFMA(Aq1, B1, O[et]);
  }

  // term 2: diagonal block, strict lower mask; k-tiles kt<=wv only
  for (int kt = 0; kt <= wv; ++kt) {
    const U16* krow = Kr + ((size_t)g * T + k0 + 16 * kt + lr) * DD;
    bf16x8 Bk0 = *(const bf16x8*)(krow + 8 * lg);
    bf16x8 Bk1 = *(const bf16x8*)(krow + 8 * lg + 32);
    f32x4 s = {0.f, 0.f, 0.f, 0.f};
    s = MFMA(Aq0, Bk0, s);
    s = MFMA(Aq1, Bk1, s);
#pragma unroll
    for (int rr = 0; rr < 4; ++rr) {
      int qi = 16 * wv + 4 * lg + rr, ki = 16 * kt + lr;
      float val = (qi > ki) ? s[rr] : 0.f;
      SW[wv][4 * lg + rr][16 * kt + lr] = f2bf(val);
    }
  }
  for (int kt = wv + 1; kt < 4; ++kt) {
#pragma unroll
    for (int rr = 0; rr < 4; ++rr)
      SW[wv][4 * lg + rr][16 * kt + lr] = 0;
  }

  // A-fragments of masked S (same-wave LDS round trip)
  bf16x8 As0 = *(const bf16x8*)&SW[wv][lr][8 * lg];
  bf16x8 As1 = *(const bf16x8*)&SW[wv][lr][8 * lg + 32];

  // PV
#pragma unroll
  for (int et = 0; et < 4; ++et) {
    bf16x8 Bv0 = *(const bf16x8*)&VT[16 * et + lr][8 * lg];
    bf16x8 Bv1 = *(const bf16x8*)&VT[16 * et + lr][8 * lg + 32];
    O[et] = MFMA(As0, Bv0, O[et]);
    O[et] = MFMA(As1, Bv1, O[et]);
  }

  // store f32 output
#pragma unroll
  for (int et = 0; et < 4; ++et)
#pragma unroll
    for (int rr = 0; rr < 4; ++rr)
      Out[((size_t)g * T + q0 + 4 * lg + rr) * DD + 16 * et + lr] = O[et][rr];
}

extern "C" void kernel_launch(void* const* d_in, const int* in_sizes, int n_in,
                              void* d_out, int out_size, void* d_ws, size_t ws_size,
                              hipStream_t stream) {
  const float* Q = (const float*)d_in[0];
  const float* K = (const float*)d_in[1];
  const float* V = (const float*)d_in[2];
  float* Out = (float*)d_out;
  U16* W  = (U16*)d_ws;
  U16* Kr = W;                 // 8.39 MB
  U16* Vb = W + 4194304;       // 8.39 MB
  U16* Xu = W + 8388608;       // 8.39 MB   (24 MiB of ws)
  k_phase1<<<G * 64, 256, 0, stream>>>(K, V, Kr, Vb, Xu);
  k_phase2b<<<1024, 256, 0, stream>>>(Xu);
  k_phase3<<<G * 64, 256, 0, stream>>>(Q, Kr, Vb, Xu, Out);
}

// Round 6
// 29.593 us; speedup vs baseline: 8.6171x; 1.0861x over previous
//
#include <hip/hip_runtime.h>

#define G 16
#define T 4096
#define DD 64

typedef __attribute__((ext_vector_type(8))) short bf16x8;
typedef __attribute__((ext_vector_type(4))) float f32x4;
typedef unsigned short U16;

__device__ __forceinline__ float bf2f(U16 u) {
  union { unsigned int u; float f; } x; x.u = ((unsigned int)u) << 16; return x.f;
}
__device__ __forceinline__ U16 f2bf(float f) {
  union { float f; unsigned int u; } x; x.f = f;
  unsigned int r = x.u + 0x7FFFu + ((x.u >> 16) & 1u);
  return (U16)(r >> 16);
}

#define MFMA(a, b, c) __builtin_amdgcn_mfma_f32_16x16x32_bf16((a), (b), (c), 0, 0, 0)

// ln(10000)/32
#define ROPE_C 0.28782313662425575f

// ---------------- Phase 1: rope K -> Kr + KrT; V -> Vb (bf16) + VT; X_b = V^T Kr ----------------
__global__ __launch_bounds__(256) void k_phase1(const float* __restrict__ K, const float* __restrict__ V,
                                                U16* __restrict__ Kr, U16* __restrict__ Vb,
                                                U16* __restrict__ Xu) {
  __shared__ __align__(16) U16 KrT[64][72];   // [d][k]
  __shared__ __align__(16) U16 VT[64][72];    // [e][k]
  int wid = blockIdx.x;            // g*64 + b
  int g = wid >> 6, b = wid & 63;
  int k0 = b * 64;
  int tid = threadIdx.x;

  int r = tid >> 2, qq = tid & 3, d0 = qq * 8;
  int t = k0 + r;
  size_t base = ((size_t)g * T + t) * DD;

  // K path: rope (inline trig) -> Kr global + KrT LDS
  {
    const float* rp = K + base;
    float x1[8], x2[8];
    *(float4*)&x1[0] = *(const float4*)(rp + d0);
    *(float4*)&x1[4] = *(const float4*)(rp + d0 + 4);
    *(float4*)&x2[0] = *(const float4*)(rp + d0 + 32);
    *(float4*)&x2[4] = *(const float4*)(rp + d0 + 36);
    bf16x8 v1, v2;
#pragma unroll
    for (int i = 0; i < 8; ++i) {
      float invf = __expf(-(float)(d0 + i) * ROPE_C);
      float ang = (float)t * invf;
      float s, c;
      __sincosf(ang, &s, &c);
      float o1 = x1[i] * c - x2[i] * s;
      float o2 = x1[i] * s + x2[i] * c;
      U16 b1 = f2bf(o1), b2 = f2bf(o2);
      v1[i] = (short)b1; v2[i] = (short)b2;
      KrT[d0 + i][r]      = b1;
      KrT[d0 + i + 32][r] = b2;
    }
    *(bf16x8*)(Kr + base + d0)      = v1;
    *(bf16x8*)(Kr + base + d0 + 32) = v2;
  }
  // V path: f32 -> bf16, Vb global + VT LDS (transposed)
  {
    const float* vp = V + base;
    float y1[8], y2[8];
    *(float4*)&y1[0] = *(const float4*)(vp + d0);
    *(float4*)&y1[4] = *(const float4*)(vp + d0 + 4);
    *(float4*)&y2[0] = *(const float4*)(vp + d0 + 32);
    *(float4*)&y2[4] = *(const float4*)(vp + d0 + 36);
    bf16x8 w1, w2;
#pragma unroll
    for (int i = 0; i < 8; ++i) {
      U16 b1 = f2bf(y1[i]), b2 = f2bf(y2[i]);
      w1[i] = (short)b1; w2[i] = (short)b2;
      VT[d0 + i][r]      = b1;
      VT[d0 + i + 32][r] = b2;
    }
    *(bf16x8*)(Vb + base + d0)      = w1;
    *(bf16x8*)(Vb + base + d0 + 32) = w2;
  }
  __syncthreads();

  int lane = tid & 63, wv = tid >> 6;
  int lr = lane & 15, lg = lane >> 4;
  bf16x8 A0 = *(const bf16x8*)&VT[16 * wv + lr][8 * lg];
  bf16x8 A1 = *(const bf16x8*)&VT[16 * wv + lr][8 * lg + 32];
#pragma unroll
  for (int dt = 0; dt < 4; ++dt) {
    bf16x8 B0 = *(const bf16x8*)&KrT[16 * dt + lr][8 * lg];
    bf16x8 B1 = *(const bf16x8*)&KrT[16 * dt + lr][8 * lg + 32];
    f32x4 acc = {0.f, 0.f, 0.f, 0.f};
    acc = MFMA(A0, B0, acc);
    acc = MFMA(A1, B1, acc);
#pragma unroll
    for (int rr = 0; rr < 4; ++rr) {
      int e = 16 * wv + 4 * lg + rr, d = 16 * dt + lr;
      Xu[((size_t)wid << 12) + e * 64 + d] = f2bf(acc[rr]);
    }
  }
}

// ---------------- Phase 2: exclusive prefix over 64 block matrices per head ----------------
// One full chain per thread; col lane-contiguous for coalescing; 64 independent
// loads issued up front (deep ILP), serial in-register prefix, coalesced stores.
__global__ __launch_bounds__(256) void k_phase2c(U16* __restrict__ Xu) {
  int tau = blockIdx.x * 256 + threadIdx.x;   // 65536 threads = 16 heads * 4096 cols
  int hd = tau >> 12, col = tau & 4095;
  size_t base = ((size_t)hd << 18) + col;
  U16 v[64];
#pragma unroll
  for (int i = 0; i < 64; ++i)
    v[i] = Xu[base + ((size_t)i << 12)];
  float run = 0.f;
#pragma unroll
  for (int i = 0; i < 64; ++i) {
    float f = bf2f(v[i]);
    Xu[base + ((size_t)i << 12)] = f2bf(run);
    run += f;
  }
}

// ---------------- Phase 3: O_b = rope(Q)_b * Sp_b + tril_strict(rope(Q)_b Kr_b^T) V_b ----------------
__global__ __launch_bounds__(256) void k_phase3(const float* __restrict__ Q, const U16* __restrict__ Kr,
                                                const U16* __restrict__ Vb, const U16* __restrict__ Xu,
                                                float* __restrict__ Out) {
  __shared__ __align__(16) U16 SP[64][72];     // Sp^T [e][d]
  __shared__ __align__(16) U16 VT[64][72];     // [e][k]
  __shared__ __align__(16) U16 SW[4][16][72];  // per-wave masked S round-trip
  int wid = blockIdx.x;
  int g = wid >> 6, b = wid & 63;
  int k0 = b * 64;
  int tid = threadIdx.x;

  // stage Sp^T (vector copy from Xu)
  {
    int r = tid >> 2, c0 = (tid & 3) * 16;
    const U16* src = Xu + ((size_t)wid << 12) + r * 64 + c0;
    *(bf16x8*)&SP[r][c0]     = *(const bf16x8*)src;
    *(bf16x8*)&SP[r][c0 + 8] = *(const bf16x8*)(src + 8);
  }
  // stage VT from bf16 Vb (vector load + scalar scatter)
  {
    int r = tid >> 2, qq = tid & 3, d0 = qq * 8;
    size_t base = ((size_t)g * T + k0 + r) * DD;
    bf16x8 a0 = *(const bf16x8*)(Vb + base + d0);
    bf16x8 a1 = *(const bf16x8*)(Vb + base + d0 + 32);
#pragma unroll
    for (int i = 0; i < 8; ++i) {
      VT[d0 + i][r]      = (U16)a0[i];
      VT[d0 + i + 32][r] = (U16)a1[i];
    }
  }

  int lane = tid & 63, wv = tid >> 6;
  int lr = lane & 15, lg = lane >> 4;
  int q0 = k0 + 16 * wv;

  // fused RoPE(Q) in-register (inline trig)
  bf16x8 Aq0, Aq1;
  {
    int t = q0 + lr;
    const float* qrow = Q + ((size_t)g * T + t) * DD;
    float x1[8], x2[8];
    *(float4*)&x1[0] = *(const float4*)(qrow + 8 * lg);
    *(float4*)&x1[4] = *(const float4*)(qrow + 8 * lg + 4);
    *(float4*)&x2[0] = *(const float4*)(qrow + 8 * lg + 32);
    *(float4*)&x2[4] = *(const float4*)(qrow + 8 * lg + 36);
#pragma unroll
    for (int i = 0; i < 8; ++i) {
      float invf = __expf(-(float)(8 * lg + i) * ROPE_C);
      float ang = (float)t * invf;
      float s, c;
      __sincosf(ang, &s, &c);
      Aq0[i] = (short)f2bf(x1[i] * c - x2[i] * s);
      Aq1[i] = (short)f2bf(x1[i] * s + x2[i] * c);
    }
  }
  __syncthreads();

  f32x4 O[4];
#pragma unroll
  for (int et = 0; et < 4; ++et) O[et] = (f32x4){0.f, 0.f, 0.f, 0.f};

  // term 1: Qr * Sp
#pragma unroll
  for (int et = 0; et < 4; ++et) {
    bf16x8 B0 = *(const bf16x8*)&SP[16 * et + lr][8 * lg];
    bf16x8 B1 = *(const bf16x8*)&SP[16 * et + lr][8 * lg + 32];
    O[et] = MFMA(Aq0, B0, O[et]);
    O[et] = MFMA(Aq1, B1, O[et]);
  }

  // term 2: diagonal block, strict lower mask; k-tiles kt<=wv only
  for (int kt = 0; kt <= wv; ++kt) {
    const U16* krow = Kr + ((size_t)g * T + k0 + 16 * kt + lr) * DD;
    bf16x8 Bk0 = *(const bf16x8*)(krow + 8 * lg);
    bf16x8 Bk1 = *(const bf16x8*)(krow + 8 * lg + 32);
    f32x4 s = {0.f, 0.f, 0.f, 0.f};
    s = MFMA(Aq0, Bk0, s);
    s = MFMA(Aq1, Bk1, s);
#pragma unroll
    for (int rr = 0; rr < 4; ++rr) {
      int qi = 16 * wv + 4 * lg + rr, ki = 16 * kt + lr;
      float val = (qi > ki) ? s[rr] : 0.f;
      SW[wv][4 * lg + rr][16 * kt + lr] = f2bf(val);
    }
  }
  for (int kt = wv + 1; kt < 4; ++kt) {
#pragma unroll
    for (int rr = 0; rr < 4; ++rr)
      SW[wv][4 * lg + rr][16 * kt + lr] = 0;
  }

  // A-fragments of masked S (same-wave LDS round trip)
  bf16x8 As0 = *(const bf16x8*)&SW[wv][lr][8 * lg];
  bf16x8 As1 = *(const bf16x8*)&SW[wv][lr][8 * lg + 32];

  // PV
#pragma unroll
  for (int et = 0; et < 4; ++et) {
    bf16x8 Bv0 = *(const bf16x8*)&VT[16 * et + lr][8 * lg];
    bf16x8 Bv1 = *(const bf16x8*)&VT[16 * et + lr][8 * lg + 32];
    O[et] = MFMA(As0, Bv0, O[et]);
    O[et] = MFMA(As1, Bv1, O[et]);
  }

  // store f32 output — non-temporal (terminal data, keep L2 for Kr/Vb/Xu)
#pragma unroll
  for (int et = 0; et < 4; ++et)
#pragma unroll
    for (int rr = 0; rr < 4; ++rr)
      __builtin_nontemporal_store(O[et][rr],
          &Out[((size_t)g * T + q0 + 4 * lg + rr) * DD + 16 * et + lr]);
}

extern "C" void kernel_launch(void* const* d_in, const int* in_sizes, int n_in,
                              void* d_out, int out_size, void* d_ws, size_t ws_size,
                              hipStream_t stream) {
  const float* Q = (const float*)d_in[0];
  const float* K = (const float*)d_in[1];
  const float* V = (const float*)d_in[2];
  float* Out = (float*)d_out;
  U16* W  = (U16*)d_ws;
  U16* Kr = W;                 // 8.39 MB
  U16* Vb = W + 4194304;       // 8.39 MB
  U16* Xu = W + 8388608;       // 8.39 MB   (24 MiB of ws)
  k_phase1<<<G * 64, 256, 0, stream>>>(K, V, Kr, Vb, Xu);
  k_phase2c<<<256, 256, 0, stream>>>(Xu);
  k_phase3<<<G * 64, 256, 0, stream>>>(Q, Kr, Vb, Xu, Out);
}